// Round 1
// baseline (590.783 us; speedup 1.0000x reference)
//
#include <hip/hip_runtime.h>
#include <math.h>

// Problem constants (B=4, S=4096, D=2048, E=64, K=2)
#define BS_TOT 16384
#define DDIM   2048
#define NEXP   64
#define TOPK   2

// Block: 512 threads = 8 waves; block owns 64 rows (lane = local row),
// each wave owns a 256-wide D-slice. Grid = 16384/64 = 512 blocks
// (2 blocks/CU, 16 waves/CU = 4/SIMD).
//
// Inner loop: per d, W[d][0..63] is wave-uniform -> compiler emits
// s_load_dwordx16 into SGPRs; x[row][d] is one VGPR; 64 v_fmac_f32 with
// SGPR operand each. This is the minimal-overhead fp32 path (no fp32 MFMA
// on CDNA4).
__global__ __launch_bounds__(512, 4)
void router_kernel(const float* __restrict__ x, const float* __restrict__ W,
                   const float* __restrict__ bias, const float* __restrict__ noise,
                   float* __restrict__ out)
{
    __shared__ float lacc[64][NEXP + 1];   // +1 pad: conflict-free atomics/reads
    const int tid  = threadIdx.x;
    const int wave = tid >> 6;             // 0..7  -> D slice
    const int lane = tid & 63;             // local row
    const int rg   = blockIdx.x;           // row group
    const int row  = (rg << 6) + lane;

    // zero the LDS accumulator
    for (int i = tid; i < 64 * (NEXP + 1); i += 512) ((float*)lacc)[i] = 0.0f;
    __syncthreads();

    float acc[NEXP];
#pragma unroll
    for (int e = 0; e < NEXP; ++e) acc[e] = 0.0f;

    const int d0 = wave * 256;
    const float* xr = x + (size_t)row * DDIM + d0;
    const float* Wr = W + (size_t)d0 * NEXP;

    for (int j = 0; j < 256; j += 4) {
        const float4 xv = *(const float4*)(xr + j);   // per-lane x, 16B
        const float* w0 = Wr + (size_t)j * NEXP;      // wave-uniform W rows
#pragma unroll
        for (int e = 0; e < NEXP; ++e) acc[e] = fmaf(xv.x, w0[e],          acc[e]);
#pragma unroll
        for (int e = 0; e < NEXP; ++e) acc[e] = fmaf(xv.y, w0[NEXP + e],   acc[e]);
#pragma unroll
        for (int e = 0; e < NEXP; ++e) acc[e] = fmaf(xv.z, w0[2*NEXP + e], acc[e]);
#pragma unroll
        for (int e = 0; e < NEXP; ++e) acc[e] = fmaf(xv.w, w0[3*NEXP + e], acc[e]);
    }

    // cross-wave reduce: lacc[row][e] += acc[e]  (ds_add_f32, 2-lane/bank via pad)
#pragma unroll
    for (int e = 0; e < NEXP; ++e) atomicAdd(&lacc[lane][e], acc[e]);
    __syncthreads();

    // ---------------- epilogue: softmax + stable top-2 ----------------
    // 512 threads = 64 rows x 8 groups; each thread handles 8 experts.
    const int r  = tid >> 3;
    const int g  = tid & 7;
    const int row2 = (rg << 6) + r;
    const int ebase = g * 8;

    float v[8];
    {
        const float* nz = noise + (size_t)row2 * NEXP + ebase;
        const float* bb = bias + ebase;
#pragma unroll
        for (int q = 0; q < 8; ++q)
            v[q] = lacc[r][ebase + q] + bb[q] + 0.1f * nz[q];
    }

    // row max across 8 experts then across the 8-lane group
    float m = v[0];
#pragma unroll
    for (int q = 1; q < 8; ++q) m = fmaxf(m, v[q]);
    m = fmaxf(m, __shfl_xor(m, 1));
    m = fmaxf(m, __shfl_xor(m, 2));
    m = fmaxf(m, __shfl_xor(m, 4));

    float p[8]; float s = 0.0f;
#pragma unroll
    for (int q = 0; q < 8; ++q) { p[q] = __expf(v[q] - m); s += p[q]; }
    s += __shfl_xor(s, 1);
    s += __shfl_xor(s, 2);
    s += __shfl_xor(s, 4);
    const float inv = 1.0f / s;

    // scores out (offset = 2*BS*K floats)
    float* sout = out + 2 * BS_TOT * TOPK + (size_t)row2 * NEXP + ebase;
    *(float4*)(sout)     = make_float4(p[0]*inv, p[1]*inv, p[2]*inv, p[3]*inv);
    *(float4*)(sout + 4) = make_float4(p[4]*inv, p[5]*inv, p[6]*inv, p[7]*inv);

    // top-2 on logits v (order-identical to scores; avoids exp rounding ties),
    // stable: lower index wins ties (matches jax.lax.top_k).
    float a1 = v[0], a2; int i1 = ebase, i2;
    if (v[1] > a1) { a2 = a1; i2 = i1; a1 = v[1]; i1 = ebase + 1; }
    else           { a2 = v[1]; i2 = ebase + 1; }
#pragma unroll
    for (int q = 2; q < 8; ++q) {
        const float vq = v[q]; const int iq = ebase + q;
        if (vq > a1)      { a2 = a1; i2 = i1; a1 = vq; i1 = iq; }
        else if (vq > a2) { a2 = vq; i2 = iq; }
    }
#pragma unroll
    for (int off = 1; off < 8; off <<= 1) {
        const float o1 = __shfl_xor(a1, off), o2 = __shfl_xor(a2, off);
        const int  oi1 = __shfl_xor(i1, off), oi2 = __shfl_xor(i2, off);
        if (o1 > a1 || (o1 == a1 && oi1 < i1)) {
            if (a1 > o2 || (a1 == o2 && i1 < oi2)) { a2 = a1; i2 = i1; }
            else                                   { a2 = o2; i2 = oi2; }
            a1 = o1; i1 = oi1;
        } else {
            if (o1 > a2 || (o1 == a2 && oi1 < i2)) { a2 = o1; i2 = oi1; }
        }
    }

    if (g == 0) {
        out[(size_t)row2 * TOPK + 0] = __expf(a1 - m) * inv;  // bitwise == scores path
        out[(size_t)row2 * TOPK + 1] = __expf(a2 - m) * inv;
        float* iout = out + BS_TOT * TOPK;                    // indices stored as floats
        iout[(size_t)row2 * TOPK + 0] = (float)i1;
        iout[(size_t)row2 * TOPK + 1] = (float)i2;
    }
}

extern "C" void kernel_launch(void* const* d_in, const int* in_sizes, int n_in,
                              void* d_out, int out_size, void* d_ws, size_t ws_size,
                              hipStream_t stream)
{
    const float* x     = (const float*)d_in[0];
    const float* W     = (const float*)d_in[1];
    const float* bias  = (const float*)d_in[2];
    const float* noise = (const float*)d_in[3];
    float* out = (float*)d_out;
    (void)in_sizes; (void)n_in; (void)out_size; (void)d_ws; (void)ws_size;

    hipLaunchKernelGGL(router_kernel, dim3(BS_TOT / 64), dim3(512), 0, stream,
                       x, W, bias, noise, out);
}

// Round 2
// 399.948 us; speedup vs baseline: 1.4771x; 1.4771x over previous
//
#include <hip/hip_runtime.h>
#include <math.h>

// Problem constants (B=4, S=4096, D=2048, E=64, K=2)
#define BS_TOT 16384
#define DDIM   2048
#define NEXP   64
#define TOPK   2

#define ROWS_PER_WAVE   8
#define WAVES_PER_BLOCK 4
#define ROWS_PER_BLOCK  (ROWS_PER_WAVE * WAVES_PER_BLOCK)   // 32
#define CHUNK           8

// Mapping: lane = expert (E=64 = one wave), wave owns 8 rows.
// Per d: w = W[d][lane] (one coalesced 256B load, L1-resident W=512KB),
// acc[r] += xs[r] * w with xs wave-uniform (readfirstlane-forced) -> s_load.
// VALU floor: 16384*2048 wave-FMAs * 2cyc / (256CU*4SIMD) / 2.4GHz = 27us.
__global__ __launch_bounds__(256, 2)
void router_kernel(const float* __restrict__ x, const float* __restrict__ W,
                   const float* __restrict__ bias, const float* __restrict__ noise,
                   float* __restrict__ out)
{
    const int tid  = threadIdx.x;
    const int lane = tid & 63;                                  // expert id
    const int wid  = __builtin_amdgcn_readfirstlane(tid >> 6);  // force SGPR
    const int row0 = blockIdx.x * ROWS_PER_BLOCK + wid * ROWS_PER_WAVE;

    const float* xbase = x + (size_t)row0 * DDIM;               // wave-uniform

    float acc[ROWS_PER_WAVE];
#pragma unroll
    for (int r = 0; r < ROWS_PER_WAVE; ++r) acc[r] = 0.0f;

    for (int d0 = 0; d0 < DDIM; d0 += CHUNK) {
        // wave-uniform x values -> scalar loads (K$), not vector L1
        float xs[ROWS_PER_WAVE][CHUNK];
#pragma unroll
        for (int r = 0; r < ROWS_PER_WAVE; ++r) {
            const float* xp = xbase + (size_t)r * DDIM + d0;
#pragma unroll
            for (int k = 0; k < CHUNK; ++k) xs[r][k] = xp[k];
        }
        const float* wp = W + (size_t)d0 * NEXP + lane;
#pragma unroll
        for (int k = 0; k < CHUNK; ++k) {
            const float w = wp[(size_t)k * NEXP];               // 256B coalesced
#pragma unroll
            for (int r = 0; r < ROWS_PER_WAVE; ++r)
                acc[r] = fmaf(xs[r][k], w, acc[r]);
        }
    }

    // ---------------- epilogue: per-row softmax + top-2, all cross-lane ----
    const float blane = bias[lane];
    float* const scores_out = out + 2 * BS_TOT * TOPK;
    float* const iout       = out + BS_TOT * TOPK;

#pragma unroll
    for (int r = 0; r < ROWS_PER_WAVE; ++r) {
        const int row = row0 + r;
        const float v = acc[r] + blane + 0.1f * noise[(size_t)row * NEXP + lane];

        float m = v;
#pragma unroll
        for (int off = 1; off < 64; off <<= 1) m = fmaxf(m, __shfl_xor(m, off));
        const float p = __expf(v - m);
        float s = p;
#pragma unroll
        for (int off = 1; off < 64; off <<= 1) s += __shfl_xor(s, off);
        const float sc = p * (1.0f / s);

        scores_out[(size_t)row * NEXP + lane] = sc;             // 256B coalesced

        // top-2 across 64 lanes on logits (order-identical to scores),
        // ties -> lower index (matches jax.lax.top_k).
        float a1 = v, a2 = -INFINITY;
        int   i1 = lane, i2 = 0x7fffffff;
#pragma unroll
        for (int off = 1; off < 64; off <<= 1) {
            const float o1 = __shfl_xor(a1, off), o2 = __shfl_xor(a2, off);
            const int  oi1 = __shfl_xor(i1, off), oi2 = __shfl_xor(i2, off);
            if (o1 > a1 || (o1 == a1 && oi1 < i1)) {
                if (a1 > o2 || (a1 == o2 && i1 < oi2)) { a2 = a1; i2 = i1; }
                else                                   { a2 = o2; i2 = oi2; }
                a1 = o1; i1 = oi1;
            } else {
                if (o1 > a2 || (o1 == a2 && oi1 < i2)) { a2 = o1; i2 = oi1; }
            }
        }
        // fetch the winners' softmax values (bitwise == scores entries)
        const float s1 = __shfl(sc, i1);
        const float s2 = __shfl(sc, i2);
        if (lane == 0) {
            out[(size_t)row * TOPK + 0]  = s1;
            out[(size_t)row * TOPK + 1]  = s2;
            iout[(size_t)row * TOPK + 0] = (float)i1;
            iout[(size_t)row * TOPK + 1] = (float)i2;
        }
    }
}

extern "C" void kernel_launch(void* const* d_in, const int* in_sizes, int n_in,
                              void* d_out, int out_size, void* d_ws, size_t ws_size,
                              hipStream_t stream)
{
    const float* x     = (const float*)d_in[0];
    const float* W     = (const float*)d_in[1];
    const float* bias  = (const float*)d_in[2];
    const float* noise = (const float*)d_in[3];
    float* out = (float*)d_out;
    (void)in_sizes; (void)n_in; (void)out_size; (void)d_ws; (void)ws_size;

    hipLaunchKernelGGL(router_kernel, dim3(BS_TOT / ROWS_PER_BLOCK), dim3(256),
                       0, stream, x, W, bias, noise, out);
}